// Round 12
// baseline (248.860 us; speedup 1.0000x reference)
//
#include <hip/hip_runtime.h>
#include <math.h>

#define NB   4
#define SEQ  2048
#define DM   512
#define KS   16
#define ROWS (NB*SEQ)   // 8192

#define NCHUNK 16
#define CLEN   (SEQ / NCHUNK)          // 128
#define CH_TOT (2 * NB * NCHUNK * DM * KS)   // 1,048,576 per array

typedef __attribute__((ext_vector_type(8))) short          bf16x8;
typedef __attribute__((ext_vector_type(8))) unsigned short u16x8;
typedef __attribute__((ext_vector_type(4))) float          f32x4;

__device__ __forceinline__ float softplus_f(float z) {
    return z > 20.f ? z : log1pf(__expf(z));
}

// f32 -> bf16 (RNE), bit-level (no NaN handling; inputs finite)
__device__ __forceinline__ unsigned short f2bf(float f) {
    unsigned int u = __builtin_bit_cast(unsigned int, f);
    u += 0x7fffu + ((u >> 16) & 1u);
    return (unsigned short)(u >> 16);
}

// ---------------------------------------------------------------------------
// Kernel 0: cast Wd (512x512 f32) -> bf16 (ushort), row-major unchanged.
// ---------------------------------------------------------------------------
__global__ __launch_bounds__(256)
void k_cast_w(const float* __restrict__ src, unsigned short* __restrict__ dst, int n)
{
    const int i = (blockIdx.x * 256 + threadIdx.x) * 8;
    if (i >= n) return;
    const float4 a = *(const float4*)(src + i);
    const float4 b = *(const float4*)(src + i + 4);
    u16x8 v;
    v[0] = f2bf(a.x); v[1] = f2bf(a.y); v[2] = f2bf(a.z); v[3] = f2bf(a.w);
    v[4] = f2bf(b.x); v[5] = f2bf(b.y); v[6] = f2bf(b.z); v[7] = f2bf(b.w);
    *(u16x8*)(dst + i) = v;
}

// ---------------------------------------------------------------------------
// Kernel 1: MFMA bf16 GEMM: deltas = softplus(toks@Wd^T + bd); dx = deltas*toks
// 128x128 tile, 256 thr = 4 waves (2x2), wave tile 64x64 (4x4 frags of
// mfma_f32_16x16x32_bf16). Grid (64,4) = 256 blocks = 1/CU exactly.
// A staged f32->bf16 in regs; Wd pre-cast bf16. LDS rows padded to 40 bf16.
// ---------------------------------------------------------------------------
#define GBM 128
#define GBN 128
#define GBK 32
#define PADK 40

__global__ __launch_bounds__(256)
void k_gemm_delta(const float* __restrict__ toks, const unsigned short* __restrict__ Wbf,
                  const float* __restrict__ bd,
                  float* __restrict__ odelta, float* __restrict__ odx)
{
    __shared__ unsigned short As[GBM][PADK];
    __shared__ unsigned short Bs[GBN][PADK];
    const int tid = threadIdx.x;
    const int rowBase = blockIdx.x * GBM;
    const int colBase = blockIdx.y * GBN;

    const int l   = tid & 63;
    const int wid = tid >> 6;          // 0..3
    const int wm  = wid >> 1;          // 0..1
    const int wn  = wid & 1;           // 0..1
    const int lr  = l & 15;            // A row / B col / D col lane part
    const int lk  = (l >> 4) * 8;      // frag k offset (8 contiguous bf16)
    const int lq  = (l >> 4) * 4;      // D row sub-offset

    // staging: thread -> (row, k-half); 2 threads cover one row's 32 k
    const int srow  = tid >> 1;        // 0..127
    const int skoff = (tid & 1) * 16;  // 0 / 16

    const float*          gA = toks + (size_t)(rowBase + srow) * DM + skoff;
    const unsigned short* gW = Wbf  + (size_t)(colBase + srow) * DM + skoff;

    const f32x4 zero4 = {0.f, 0.f, 0.f, 0.f};
    f32x4 acc[4][4];
    #pragma unroll
    for (int i = 0; i < 4; ++i)
        #pragma unroll
        for (int j = 0; j < 4; ++j) acc[i][j] = zero4;

    // prefetch tile 0
    float4 pa0 = *(const float4*)(gA);
    float4 pa1 = *(const float4*)(gA + 4);
    float4 pa2 = *(const float4*)(gA + 8);
    float4 pa3 = *(const float4*)(gA + 12);
    u16x8  pw0 = *(const u16x8*)(gW);
    u16x8  pw1 = *(const u16x8*)(gW + 8);

    for (int e0 = 0; e0 < DM; e0 += GBK) {
        __syncthreads();   // previous iteration done reading LDS
        u16x8 va, vb;
        va[0] = f2bf(pa0.x); va[1] = f2bf(pa0.y); va[2] = f2bf(pa0.z); va[3] = f2bf(pa0.w);
        va[4] = f2bf(pa1.x); va[5] = f2bf(pa1.y); va[6] = f2bf(pa1.z); va[7] = f2bf(pa1.w);
        vb[0] = f2bf(pa2.x); vb[1] = f2bf(pa2.y); vb[2] = f2bf(pa2.z); vb[3] = f2bf(pa2.w);
        vb[4] = f2bf(pa3.x); vb[5] = f2bf(pa3.y); vb[6] = f2bf(pa3.z); vb[7] = f2bf(pa3.w);
        *(u16x8*)&As[srow][skoff]     = va;
        *(u16x8*)&As[srow][skoff + 8] = vb;
        *(u16x8*)&Bs[srow][skoff]     = pw0;
        *(u16x8*)&Bs[srow][skoff + 8] = pw1;
        __syncthreads();

        // prefetch next tile; latency hides under ds_reads + 16 MFMA
        if (e0 + GBK < DM) {
            pa0 = *(const float4*)(gA + e0 + GBK);
            pa1 = *(const float4*)(gA + e0 + GBK + 4);
            pa2 = *(const float4*)(gA + e0 + GBK + 8);
            pa3 = *(const float4*)(gA + e0 + GBK + 12);
            pw0 = *(const u16x8*)(gW + e0 + GBK);
            pw1 = *(const u16x8*)(gW + e0 + GBK + 8);
        }

        bf16x8 af[4], bfr[4];
        #pragma unroll
        for (int f = 0; f < 4; ++f)
            af[f] = *(const bf16x8*)&As[wm * 64 + f * 16 + lr][lk];
        #pragma unroll
        for (int f = 0; f < 4; ++f)
            bfr[f] = *(const bf16x8*)&Bs[wn * 64 + f * 16 + lr][lk];

        #pragma unroll
        for (int fm = 0; fm < 4; ++fm)
            #pragma unroll
            for (int fn = 0; fn < 4; ++fn)
                acc[fm][fn] = __builtin_amdgcn_mfma_f32_16x16x32_bf16(
                    af[fm], bfr[fn], acc[fm][fn], 0, 0, 0);
    }

    // epilogue: D lane mapping row=(l>>4)*4+r, col=l&15 (m89-verified)
    #pragma unroll
    for (int fn = 0; fn < 4; ++fn) {
        const int col = colBase + wn * 64 + fn * 16 + lr;
        const float bias = bd[col];
        #pragma unroll
        for (int fm = 0; fm < 4; ++fm) {
            const int row0 = rowBase + wm * 64 + fm * 16 + lq;
            #pragma unroll
            for (int r = 0; r < 4; ++r) {
                const size_t off = (size_t)(row0 + r) * DM + col;
                const float dl = softplus_f(acc[fm][fn][r] + bias);
                odelta[off] = dl;
                odx[off]    = dl * toks[off];
            }
        }
    }
}

// ---------------------------------------------------------------------------
// Kernel 2: Bs = toks @ W_B^T, Cs = toks @ W_C^T   ([ROWS,16] each), f32.
// ---------------------------------------------------------------------------
__global__ __launch_bounds__(256)
void k_bc(const float* __restrict__ toks, const float* __restrict__ WB,
          const float* __restrict__ WC, float* __restrict__ oB,
          float* __restrict__ oC)
{
    const int tid = threadIdx.x;
    const int k  = tid & 15;
    const int rl = tid >> 4;
    const int row = blockIdx.x * 16 + rl;
    const float* tp = toks + (size_t)row * DM;
    const float* wb = WB + (size_t)k * DM;
    const float* wc = WC + (size_t)k * DM;
    float ab = 0.f, ac = 0.f;
    #pragma unroll 4
    for (int e = 0; e < DM; e += 4) {
        float4 tv = *(const float4*)(tp + e);
        float4 bv = *(const float4*)(wb + e);
        float4 cv = *(const float4*)(wc + e);
        ab = fmaf(tv.x, bv.x, ab); ab = fmaf(tv.y, bv.y, ab);
        ab = fmaf(tv.z, bv.z, ab); ab = fmaf(tv.w, bv.w, ab);
        ac = fmaf(tv.x, cv.x, ac); ac = fmaf(tv.y, cv.y, ac);
        ac = fmaf(tv.z, cv.z, ac); ac = fmaf(tv.w, cv.w, ac);
    }
    oB[(size_t)row * KS + k] = ab;
    oC[(size_t)row * KS + k] = ac;
}

// ---------------------------------------------------------------------------
// Kernel 3a: chunked scan, pass 1. Thread = (dir,n,chunk,d,k).
// Chunk summary: h_end = P*h0 + Q ; sum_t c_t h_t = R*h0 + S.
// ---------------------------------------------------------------------------
__global__ __launch_bounds__(256)
void k_scan_chunk(const float* __restrict__ de, const float* __restrict__ dx,
                  const float* __restrict__ Bsp, const float* __restrict__ Csp,
                  const float* __restrict__ logA,
                  float* __restrict__ oP, float* __restrict__ oQ,
                  float* __restrict__ oR, float* __restrict__ oS)
{
    const int g     = blockIdx.x * blockDim.x + threadIdx.x;
    const int k     = g & 15;
    const int d     = (g >> 4) & (DM - 1);
    const int chunk = (g >> 13) & (NCHUNK - 1);
    const int n     = (g >> 17) & (NB - 1);
    const int dir   = (g >> 19) & 1;

    const float Ac = -__expf(logA[d * KS + k]);

    const int sgn = dir ? -1 : 1;
    const int t0  = dir ? (SEQ - 1 - chunk * CLEN) : (chunk * CLEN);
    const size_t rbase = (size_t)n * SEQ + t0;

    const float* pd = de  + rbase * DM + d;
    const float* px = dx  + rbase * DM + d;
    const float* pb = Bsp + rbase * KS + k;
    const float* pc = Csp + rbase * KS + k;
    const int sD = sgn * DM;
    const int sK = sgn * KS;

    float A = 1.f, u = 0.f, R = 0.f, S = 0.f;
    #pragma unroll 4
    for (int t = 0; t < CLEN; ++t) {
        const float dev = *pd;
        const float bxv = *px;
        const float bv  = *pb;
        const float cv  = *pc;
        pd += sD; px += sD; pb += sK; pc += sK;
        const float a = __expf(dev * Ac);
        u = fmaf(a, u, bxv * bv);
        A = A * a;
        R = fmaf(cv, A, R);
        S = fmaf(cv, u, S);
    }

    const size_t idx = ((((size_t)dir * NB + n) * NCHUNK + chunk) * DM + d) * KS + k;
    oP[idx] = A; oQ[idx] = u; oR[idx] = R; oS[idx] = S;
}

// ---------------------------------------------------------------------------
// Kernel 3b: compose chunk summaries in scan order; k-reduce; atomicAdd.
// ---------------------------------------------------------------------------
__global__ __launch_bounds__(256)
void k_scan_fix(const float* __restrict__ oP, const float* __restrict__ oQ,
                const float* __restrict__ oR, const float* __restrict__ oS,
                float* __restrict__ out)
{
    const int g   = blockIdx.x * blockDim.x + threadIdx.x;
    const int k   = g & 15;
    const int d   = (g >> 4) & (DM - 1);
    const int n   = (g >> 13) & (NB - 1);
    const int dir = (g >> 15) & 1;

    size_t idx = ((((size_t)dir * NB + n) * NCHUNK) * DM + d) * KS + k;
    const size_t stride = (size_t)DM * KS;

    float h = 0.f, acc = 0.f;
    #pragma unroll
    for (int c = 0; c < NCHUNK; ++c) {
        const float P = oP[idx];
        const float Q = oQ[idx];
        const float R = oR[idx];
        const float S = oS[idx];
        idx += stride;
        acc = fmaf(R, h, acc) + S;
        h   = fmaf(P, h, Q);
    }

    acc += __shfl_xor(acc, 1);
    acc += __shfl_xor(acc, 2);
    acc += __shfl_xor(acc, 4);
    acc += __shfl_xor(acc, 8);

    if (k == 0)
        atomicAdd(&out[n * DM + d], acc * (1.0f / SEQ));
}

// ---------------------------------------------------------------------------
extern "C" void kernel_launch(void* const* d_in, const int* in_sizes, int n_in,
                              void* d_out, int out_size, void* d_ws, size_t ws_size,
                              hipStream_t stream) {
    const float* toks = (const float*)d_in[0];
    const float* logA = (const float*)d_in[1];
    const float* WB   = (const float*)d_in[2];
    const float* WC   = (const float*)d_in[3];
    const float* Wd   = (const float*)d_in[4];
    const float* bd   = (const float*)d_in[5];
    float* out = (float*)d_out;

    float* ws    = (float*)d_ws;
    float* wdel  = ws;                                   // ROWS*DM
    float* wdx   = wdel + (size_t)ROWS * DM;             // ROWS*DM
    float* wB    = wdx  + (size_t)ROWS * DM;             // ROWS*KS
    float* wC    = wB   + (size_t)ROWS * KS;             // ROWS*KS
    float* wP    = wC   + (size_t)ROWS * KS;             // CH_TOT each
    float* wQ    = wP   + (size_t)CH_TOT;
    float* wR    = wQ   + (size_t)CH_TOT;
    float* wS    = wR   + (size_t)CH_TOT;
    unsigned short* wWbf = (unsigned short*)(wS + (size_t)CH_TOT);  // 512*512 bf16

    hipMemsetAsync(d_out, 0, sizeof(float) * NB * DM, stream);

    k_cast_w<<<(DM * DM) / (256 * 8), 256, 0, stream>>>(Wd, wWbf, DM * DM);
    k_gemm_delta<<<dim3(ROWS / GBM, DM / GBN), 256, 0, stream>>>(
        toks, wWbf, bd, wdel, wdx);
    k_bc<<<ROWS / 16, 256, 0, stream>>>(toks, WB, WC, wB, wC);
    k_scan_chunk<<<(2 * NB * NCHUNK * DM * KS) / 256, 256, 0, stream>>>(
        wdel, wdx, wB, wC, logA, wP, wQ, wR, wS);
    k_scan_fix<<<(2 * NB * DM * KS) / 256, 256, 0, stream>>>(wP, wQ, wR, wS, out);
}